// Round 4
// baseline (323.176 us; speedup 1.0000x reference)
//
#include <hip/hip_runtime.h>

#define NTOK 49
#define CH   128
#define NHEAD 4
#define SCALE 0.17677669529663687f   // 32^-0.5

typedef __bf16 bf16x8 __attribute__((ext_vector_type(8)));
typedef short  s16x8  __attribute__((ext_vector_type(8)));
typedef float  f32x4  __attribute__((ext_vector_type(4)));
// may_alias: LDS regions are retyped across phases (q/k -> P/vT); keep store<->load order
typedef s16x8 s16x8_a __attribute__((may_alias));
typedef unsigned short u16_a __attribute__((may_alias));

__device__ __forceinline__ unsigned short f2bf(float f) {
  unsigned int u = __builtin_bit_cast(unsigned int, f);
  u += 0x7FFFu + ((u >> 16) & 1u);          // RNE
  return (unsigned short)(u >> 16);
}

__device__ __forceinline__ f32x4 mfma_bf16(s16x8 a, s16x8 b, f32x4 c) {
  return __builtin_amdgcn_mfma_f32_16x16x32_bf16(
      __builtin_bit_cast(bf16x8, a), __builtin_bit_cast(bf16x8, b), c, 0, 0, 0);
}

// ---------------- prep: weights -> bf16 transposed, rpb expand (baseline verbatim) ------
// ws layout: wT bf16[384][128] @0 ; pT bf16[128][128] @98304B ; rpb f32[4][49*49] @131072B
__global__ void prep_kernel(const float* __restrict__ qkv_w,
                            const float* __restrict__ proj_w,
                            const float* __restrict__ bias_table,
                            unsigned short* __restrict__ wT,
                            unsigned short* __restrict__ pT,
                            float* __restrict__ rpb) {
  int t = blockIdx.x * 256 + threadIdx.x;
  if (t < 384 * 128) {
    int n = t >> 7, k = t & 127;
    float v = qkv_w[k * 384 + n];
    if (n < 128) v *= SCALE;                 // fold q scale into Wq
    wT[n * 128 + k] = f2bf(v);
  } else if (t < 384 * 128 + 128 * 128) {
    int u = t - 384 * 128;
    int n = u >> 7, k = u & 127;
    pT[n * 128 + k] = f2bf(proj_w[k * 128 + n]);
  } else if (t < 384 * 128 + 128 * 128 + NHEAD * NTOK * NTOK) {
    int u = t - (384 * 128 + 128 * 128);
    int h = u / (NTOK * NTOK);
    int ij = u % (NTOK * NTOK);
    int i = ij / NTOK, j = ij % NTOK;
    int idx = (i / 7 - j / 7 + 6) * 13 + (i % 7 - j % 7 + 6);
    rpb[h * (NTOK * NTOK) + ij] = bias_table[idx * NHEAD + h];
  }
}

// ---------------- fused: qkv + attention + proj, 1 window/WG, 1 head/wave ----------------
// LDS = 54272 B = 106*512 exactly -> 3 blocks/CU (LDS allocation granularity is 512 B;
// round-3's 54288 B request rounded to 54784 -> only 2 blocks/CU, perf-neutral vs baseline).
//   Xs bf16[49][136] @0 — usable bytes end at short 6656 (last row's tail pad is dead)
//   per-wave priv @ short 6656 + wave*5120 (10240 B each):
//     phase 1: q[64][40] @0, k[64][40] @+2560 shorts
//     phase 2: P-half[64][40] @0 (over q), vT[32][72] @+2560 (over k)
//   AO [64][136] @0 (over Xs + wave0 priv) after barrier 2.
__global__ __launch_bounds__(256, 3)
void attn_fused_kernel(const float* __restrict__ x,
                       const float* __restrict__ qkv_b,
                       const float* __restrict__ proj_b,
                       const float* __restrict__ mask,
                       const unsigned short* __restrict__ wT,
                       const unsigned short* __restrict__ pT,
                       const float* __restrict__ rpb,
                       float* __restrict__ out) {
  __shared__ __align__(16) char smem_raw[54272];
  unsigned short* const smem = (unsigned short*)smem_raw;

  const int w    = blockIdx.x;
  const int tid  = threadIdx.x;
  const int wave = tid >> 6;        // == head
  const int lane = tid & 63;
  const int quad = lane >> 4;
  const int l16  = lane & 15;
  const int h    = wave;
  const int wq8  = quad * 8;

  unsigned short* const Xs   = smem;                         // [49][136] (tail pad dead)
  unsigned short* const priv = smem + 6656 + wave * 5120;    // 10240 B / wave
  unsigned short* const qs   = priv;                         // q [64][40]
  unsigned short* const ks   = priv + 2560;                  // k [64][40]
  unsigned short* const ps   = priv;                         // P-half [64][40] (over q)
  unsigned short* const vt   = priv + 2560;                  // vT [32][72]   (over k)
  unsigned short* const ao   = smem;                         // AO [64][136] (barrier 2+)

  const f32x4 fzero = {0.f, 0.f, 0.f, 0.f};

  // ---- stage x[w] fp32 -> bf16 LDS (rows 0..48 only; reads clamp instead of pad) ----
  {
    const float* xw = x + (size_t)w * (NTOK * CH);
    for (int t = tid; t < NTOK * 32; t += 256) {
      const int row = t >> 5;
      const int c4  = (t & 31) << 2;
      const float4 v = *(const float4*)(xw + row * CH + c4);
      ushort4 pk;
      pk.x = f2bf(v.x); pk.y = f2bf(v.y); pk.z = f2bf(v.z); pk.w = f2bf(v.w);
      *(ushort4*)(Xs + row * 136 + c4) = pk;
    }
  }
  __syncthreads();   // barrier 1: Xs published

  int xrow[4];
#pragma unroll
  for (int mt = 0; mt < 4; ++mt) {
    const int rr = mt * 16 + l16;
    xrow[mt] = (rr < NTOK ? rr : NTOK - 1) * 136;   // clamp: finite garbage, fully masked
  }

  // ================= QKV pass A: q and k (share x-fragment loads) =================
  f32x4 accq[4][2], acck[4][2];
#pragma unroll
  for (int mt = 0; mt < 4; ++mt)
#pragma unroll
    for (int nt = 0; nt < 2; ++nt) { accq[mt][nt] = fzero; acck[mt][nt] = fzero; }
#pragma unroll
  for (int kt = 0; kt < 4; ++kt) {
    s16x8 a[4], bq[2], bk[2];
#pragma unroll
    for (int mt = 0; mt < 4; ++mt)
      a[mt] = *(const s16x8*)(Xs + xrow[mt] + kt * 32 + wq8);
#pragma unroll
    for (int nt = 0; nt < 2; ++nt) {
      const int rowq = h * 32 + nt * 16 + l16;
      bq[nt] = *(const s16x8*)(wT + (size_t)rowq * 128 + kt * 32 + wq8);
      bk[nt] = *(const s16x8*)(wT + (size_t)(128 + rowq) * 128 + kt * 32 + wq8);
    }
#pragma unroll
    for (int mt = 0; mt < 4; ++mt)
#pragma unroll
      for (int nt = 0; nt < 2; ++nt) {
        accq[mt][nt] = mfma_bf16(a[mt], bq[nt], accq[mt][nt]);
        acck[mt][nt] = mfma_bf16(a[mt], bk[nt], acck[mt][nt]);
      }
  }
#pragma unroll
  for (int nt = 0; nt < 2; ++nt) {
    const int col = nt * 16 + l16;
    const float bq_ = qkv_b[h * 32 + col] * SCALE;   // Wq pre-scaled; scale bias to match
    const float bk_ = qkv_b[128 + h * 32 + col];
#pragma unroll
    for (int mt = 0; mt < 4; ++mt)
#pragma unroll
      for (int r = 0; r < 4; ++r) {
        const int row = mt * 16 + quad * 4 + r;
        *(u16_a*)(qs + row * 40 + col) = f2bf(accq[mt][nt][r] + bq_);
        *(u16_a*)(ks + row * 40 + col) = f2bf(acck[mt][nt][r] + bk_);
      }
  }

  // ================= QKV pass B: v (kept in registers until after kf drain) =============
  f32x4 accv[4][2];
#pragma unroll
  for (int mt = 0; mt < 4; ++mt)
#pragma unroll
    for (int nt = 0; nt < 2; ++nt) accv[mt][nt] = fzero;
#pragma unroll
  for (int kt = 0; kt < 4; ++kt) {
    s16x8 a[4], bv[2];
#pragma unroll
    for (int mt = 0; mt < 4; ++mt)
      a[mt] = *(const s16x8*)(Xs + xrow[mt] + kt * 32 + wq8);
#pragma unroll
    for (int nt = 0; nt < 2; ++nt)
      bv[nt] = *(const s16x8*)(wT + (size_t)(256 + h * 32 + nt * 16 + l16) * 128 + kt * 32 + wq8);
#pragma unroll
    for (int mt = 0; mt < 4; ++mt)
#pragma unroll
      for (int nt = 0; nt < 2; ++nt)
        accv[mt][nt] = mfma_bf16(a[mt], bv[nt], accv[mt][nt]);
  }

  // ---- q/k fragments -> regs, then drain LDS reads before any aliasing store ----
  s16x8 qf[4], kf[4];
#pragma unroll
  for (int t4 = 0; t4 < 4; ++t4) {
    qf[t4] = *(const s16x8_a*)(qs + (t4 * 16 + l16) * 40 + wq8);
    kf[t4] = *(const s16x8_a*)(ks + (t4 * 16 + l16) * 40 + wq8);
  }
  asm volatile("s_waitcnt lgkmcnt(0)" ::: "memory");   // WAR fence (within-wave)

  // ---- vT (baseline v epilogue, retargeted over the k region) ----
#pragma unroll
  for (int nt = 0; nt < 2; ++nt) {
    const float bv_ = qkv_b[256 + h * 32 + nt * 16 + l16];
#pragma unroll
    for (int mt = 0; mt < 4; ++mt)
#pragma unroll
      for (int r = 0; r < 4; ++r) {
        const int row = mt * 16 + quad * 4 + r;     // token
        const int col = nt * 16 + l16;              // d
        *(u16_a*)(vt + col * 72 + row) = f2bf(accv[mt][nt][r] + bv_);
      }
  }

  // ---- S = q k^T (baseline) ----
  f32x4 s[4][4];
#pragma unroll
  for (int mt = 0; mt < 4; ++mt)
#pragma unroll
    for (int nt = 0; nt < 4; ++nt)
      s[mt][nt] = mfma_bf16(qf[mt], kf[nt], fzero);

  // ---- logits + rpb + mask; row softmax (baseline); P half0 -> LDS, half1 held ----
  const float* maskw = mask + (size_t)(w & 63) * (NTOK * NTOK);
  const float* rpbh  = rpb + h * (NTOK * NTOK);
  float rinv[4][4];
  unsigned int pHold[4][4];                          // packed bf16x2: j-tiles 2,3
#pragma unroll
  for (int mt = 0; mt < 4; ++mt) {
#pragma unroll
    for (int r = 0; r < 4; ++r) {
      const int i = mt * 16 + quad * 4 + r;
      float vals[4];
      float vmax = -1e30f;
#pragma unroll
      for (int nt = 0; nt < 4; ++nt) {
        const int j = nt * 16 + l16;
        float v = -1e30f;                            // pad cols -> P=0
        if (i < NTOK && j < NTOK) {
          const int ij = i * NTOK + j;
          v = s[mt][nt][r] + rpbh[ij] + maskw[ij];
        }
        vals[nt] = v;
        vmax = fmaxf(vmax, v);
      }
#pragma unroll
      for (int off = 1; off < 16; off <<= 1)         // row spans 16 lanes of this quad-group
        vmax = fmaxf(vmax, __shfl_xor(vmax, off, 64));
      float rsum = 0.f;
#pragma unroll
      for (int nt = 0; nt < 4; ++nt) {
        const float e = __expf(vals[nt] - vmax);
        vals[nt] = e;
        rsum += e;
      }
#pragma unroll
      for (int off = 1; off < 16; off <<= 1)
        rsum += __shfl_xor(rsum, off, 64);
      rinv[mt][r] = 1.f / rsum;                      // normalization deferred to AO write
      *(u16_a*)(ps + i * 40 + l16)      = f2bf(vals[0]);
      *(u16_a*)(ps + i * 40 + 16 + l16) = f2bf(vals[1]);
      pHold[mt][r] = (unsigned int)f2bf(vals[2]) | ((unsigned int)f2bf(vals[3]) << 16);
    }
  }

  // ================= O = P v (M=64,N=32,K=64), half-K ping-pong on P buffer =============
  f32x4 o[4][2];
#pragma unroll
  for (int mt = 0; mt < 4; ++mt)
#pragma unroll
    for (int nt = 0; nt < 2; ++nt) o[mt][nt] = fzero;
  {
    s16x8 pf[4], vf[2];
#pragma unroll
    for (int mt = 0; mt < 4; ++mt)
      pf[mt] = *(const s16x8_a*)(ps + (mt * 16 + l16) * 40 + wq8);
#pragma unroll
    for (int nt = 0; nt < 2; ++nt)
      vf[nt] = *(const s16x8_a*)(vt + (nt * 16 + l16) * 72 + wq8);
#pragma unroll
    for (int mt = 0; mt < 4; ++mt)
#pragma unroll
      for (int nt = 0; nt < 2; ++nt)
        o[mt][nt] = mfma_bf16(pf[mt], vf[nt], o[mt][nt]);
  }
  asm volatile("" ::: "memory");       // kt0 reads ordered before half-1 stores
#pragma unroll
  for (int mt = 0; mt < 4; ++mt)
#pragma unroll
    for (int r = 0; r < 4; ++r) {
      const int i = mt * 16 + quad * 4 + r;
      *(u16_a*)(ps + i * 40 + l16)      = (unsigned short)(pHold[mt][r] & 0xFFFFu);
      *(u16_a*)(ps + i * 40 + 16 + l16) = (unsigned short)(pHold[mt][r] >> 16);
    }
  asm volatile("" ::: "memory");       // stores ordered before kt1 reads
  {
    s16x8 pf[4], vf[2];
#pragma unroll
    for (int mt = 0; mt < 4; ++mt)
      pf[mt] = *(const s16x8_a*)(ps + (mt * 16 + l16) * 40 + wq8);
#pragma unroll
    for (int nt = 0; nt < 2; ++nt)
      vf[nt] = *(const s16x8_a*)(vt + (nt * 16 + l16) * 72 + 32 + wq8);
#pragma unroll
    for (int mt = 0; mt < 4; ++mt)
#pragma unroll
      for (int nt = 0; nt < 2; ++nt)
        o[mt][nt] = mfma_bf16(pf[mt], vf[nt], o[mt][nt]);
  }

  // ================= AO -> LDS (baseline), proj (baseline) =================
  __syncthreads();                     // barrier 2: all waves done with priv/Xs
#pragma unroll
  for (int mt = 0; mt < 4; ++mt)
#pragma unroll
    for (int nt = 0; nt < 2; ++nt)
#pragma unroll
      for (int r = 0; r < 4; ++r) {
        const int row = mt * 16 + quad * 4 + r;
        *(u16_a*)(ao + row * 136 + h * 32 + nt * 16 + l16) = f2bf(o[mt][nt][r] * rinv[mt][r]);
      }
  __syncthreads();                     // barrier 3: AO published

  f32x4 po[4][2];
#pragma unroll
  for (int mt = 0; mt < 4; ++mt)
#pragma unroll
    for (int nt = 0; nt < 2; ++nt) po[mt][nt] = fzero;
#pragma unroll
  for (int kt = 0; kt < 4; ++kt) {
    s16x8 a[4], b[2];
#pragma unroll
    for (int mt = 0; mt < 4; ++mt)
      a[mt] = *(const s16x8_a*)(ao + (mt * 16 + l16) * 136 + kt * 32 + wq8);
#pragma unroll
    for (int nt = 0; nt < 2; ++nt)
      b[nt] = *(const s16x8*)(pT + (size_t)(h * 32 + nt * 16 + l16) * 128 + kt * 32 + wq8);
#pragma unroll
    for (int mt = 0; mt < 4; ++mt)
#pragma unroll
      for (int nt = 0; nt < 2; ++nt)
        po[mt][nt] = mfma_bf16(a[mt], b[nt], po[mt][nt]);
  }
  float* outw = out + (size_t)w * (NTOK * CH);
#pragma unroll
  for (int nt = 0; nt < 2; ++nt) {
    const int col = h * 32 + nt * 16 + l16;
    const float pb = proj_b[col];
#pragma unroll
    for (int mt = 0; mt < 4; ++mt)
#pragma unroll
      for (int r = 0; r < 4; ++r) {
        const int row = mt * 16 + quad * 4 + r;
        if (row < NTOK) outw[row * CH + col] = po[mt][nt][r] + pb;
      }
  }
}

extern "C" void kernel_launch(void* const* d_in, const int* in_sizes, int n_in,
                              void* d_out, int out_size, void* d_ws, size_t ws_size,
                              hipStream_t stream) {
  (void)in_sizes; (void)n_in; (void)out_size; (void)ws_size;
  const float* x          = (const float*)d_in[0];
  const float* qkv_w      = (const float*)d_in[1];
  const float* qkv_b      = (const float*)d_in[2];
  const float* proj_w     = (const float*)d_in[3];
  const float* proj_b     = (const float*)d_in[4];
  const float* bias_table = (const float*)d_in[5];
  const float* mask       = (const float*)d_in[6];
  float* out = (float*)d_out;

  unsigned short* wT = (unsigned short*)d_ws;          // 384*128 bf16
  unsigned short* pT = wT + 384 * 128;                 // 128*128 bf16
  float* rpb = (float*)(pT + 128 * 128);               // 4*49*49 f32 (@131072 B)

  const int prep_items = 384 * 128 + 128 * 128 + NHEAD * NTOK * NTOK;
  prep_kernel<<<(prep_items + 255) / 256, 256, 0, stream>>>(qkv_w, proj_w, bias_table,
                                                            wT, pT, rpb);
  attn_fused_kernel<<<4096, 256, 0, stream>>>(x, qkv_b, proj_b, mask, wT, pT, rpb, out);
}

// Round 6
// 294.789 us; speedup vs baseline: 1.0963x; 1.0963x over previous
//
#include <hip/hip_runtime.h>

#define NTOK 49
#define CH   128
#define NHEAD 4
#define SCALE 0.17677669529663687f   // 32^-0.5

typedef __bf16 bf16x8 __attribute__((ext_vector_type(8)));
typedef short  s16x8  __attribute__((ext_vector_type(8)));
typedef float  f32x4  __attribute__((ext_vector_type(4)));
// may_alias: LDS regions are retyped across phases (q -> k -> P; vT); keep store<->load order
typedef s16x8 s16x8_a __attribute__((may_alias));
typedef unsigned short u16_a __attribute__((may_alias));

// Manual RNE f32->bf16 — the ONLY conversion verified on this harness.
// (v_cvt_pk_bf16_f32 inline asm correlated 3-for-3 with NaN failures: r0/r1/r5.
//  Its dst.hi semantics are unverified on gfx950; do not reintroduce without an
//  isolated A/B probe.)
__device__ __forceinline__ unsigned short f2bf(float f) {
  unsigned int u = __builtin_bit_cast(unsigned int, f);
  u += 0x7FFFu + ((u >> 16) & 1u);          // RNE
  return (unsigned short)(u >> 16);
}

__device__ __forceinline__ f32x4 mfma_bf16(s16x8 a, s16x8 b, f32x4 c) {
  return __builtin_amdgcn_mfma_f32_16x16x32_bf16(
      __builtin_bit_cast(bf16x8, a), __builtin_bit_cast(bf16x8, b), c, 0, 0, 0);
}

// ---------------- prep: weights -> bf16 transposed, rpb expand (baseline verbatim) ------
// ws layout: wT bf16[384][128] @0 ; pT bf16[128][128] @98304B ; rpb f32[4][49*49] @131072B
__global__ void prep_kernel(const float* __restrict__ qkv_w,
                            const float* __restrict__ proj_w,
                            const float* __restrict__ bias_table,
                            unsigned short* __restrict__ wT,
                            unsigned short* __restrict__ pT,
                            float* __restrict__ rpb) {
  int t = blockIdx.x * 256 + threadIdx.x;
  if (t < 384 * 128) {
    int n = t >> 7, k = t & 127;
    float v = qkv_w[k * 384 + n];
    if (n < 128) v *= SCALE;                 // fold q scale into Wq
    wT[n * 128 + k] = f2bf(v);
  } else if (t < 384 * 128 + 128 * 128) {
    int u = t - 384 * 128;
    int n = u >> 7, k = u & 127;
    pT[n * 128 + k] = f2bf(proj_w[k * 128 + n]);
  } else if (t < 384 * 128 + 128 * 128 + NHEAD * NTOK * NTOK) {
    int u = t - (384 * 128 + 128 * 128);
    int h = u / (NTOK * NTOK);
    int ij = u % (NTOK * NTOK);
    int i = ij / NTOK, j = ij % NTOK;
    int idx = (i / 7 - j / 7 + 6) * 13 + (i % 7 - j % 7 + 6);
    rpb[h * (NTOK * NTOK) + ij] = bias_table[idx * NHEAD + h];
  }
}

// ---------------- fused: qkv + attention + proj, 1 window/WG, 1 head/wave ----------------
// LDS = 52224 B (102*512). 3 blocks/CU needs 156672 <= 163840 with 7 KiB slack
// (r4's 54272*3 = 162816 left only 1 KiB slack and the HW still ran 2 blocks/CU ->
//  evidence of a small per-CU LDS reservation; this version gives real headroom).
//   Xs bf16[49][136] @0 — usable shorts end at 6656 (last row's tail pad dead)
//   per-wave priv @ short 6656 + wave*4864 (9728 B each):
//     buf0 [64][40] (5120 B): q staging -> k staging -> P-half   (time-multiplexed;
//       q/k never coexist in LDS — only qf/kf register fragments coexist)
//     buf1 [32][72] (4608 B): vT
//   AO [64][136] @0 (over Xs + wave0 priv) after barrier 2.
// Numeric paths bit-identical to the verified r4 kernel (manual RNE everywhere).
__global__ __launch_bounds__(256, 3)
void attn_fused_kernel(const float* __restrict__ x,
                       const float* __restrict__ qkv_b,
                       const float* __restrict__ proj_b,
                       const float* __restrict__ mask,
                       const unsigned short* __restrict__ wT,
                       const unsigned short* __restrict__ pT,
                       const float* __restrict__ rpb,
                       float* __restrict__ out) {
  __shared__ __align__(16) char smem_raw[52224];
  unsigned short* const smem = (unsigned short*)smem_raw;

  const int w    = blockIdx.x;
  const int tid  = threadIdx.x;
  const int wave = tid >> 6;        // == head
  const int lane = tid & 63;
  const int quad = lane >> 4;
  const int l16  = lane & 15;
  const int h    = wave;
  const int wq8  = quad * 8;

  unsigned short* const Xs   = smem;                         // [49][136] (tail pad dead)
  unsigned short* const priv = smem + 6656 + wave * 4864;    // 9728 B / wave
  unsigned short* const qs   = priv;                         // buf0: q [64][40]
  unsigned short* const ks   = priv;                         // buf0: k [64][40] (after qf)
  unsigned short* const ps   = priv;                         // buf0: P-half [64][40]
  unsigned short* const vt   = priv + 2560;                  // buf1: vT [32][72]
  unsigned short* const ao   = smem;                         // AO [64][136] (barrier 2+)

  const f32x4 fzero = {0.f, 0.f, 0.f, 0.f};

  // ---- stage x[w] fp32 -> bf16 LDS (rows 0..48 only; reads clamp instead of pad) ----
  {
    const float* xw = x + (size_t)w * (NTOK * CH);
    for (int t = tid; t < NTOK * 32; t += 256) {
      const int row = t >> 5;
      const int c4  = (t & 31) << 2;
      const float4 v = *(const float4*)(xw + row * CH + c4);
      ushort4 pk;
      pk.x = f2bf(v.x); pk.y = f2bf(v.y); pk.z = f2bf(v.z); pk.w = f2bf(v.w);
      *(ushort4*)(Xs + row * 136 + c4) = pk;
    }
  }
  __syncthreads();   // barrier 1: Xs published

  int xrow[4];
#pragma unroll
  for (int mt = 0; mt < 4; ++mt) {
    const int rr = mt * 16 + l16;
    xrow[mt] = (rr < NTOK ? rr : NTOK - 1) * 136;   // clamp: finite garbage, fully masked
  }

  // ================= QKV pass A1: q -> buf0 -> qf regs =================
  f32x4 accq[4][2];
#pragma unroll
  for (int mt = 0; mt < 4; ++mt)
#pragma unroll
    for (int nt = 0; nt < 2; ++nt) accq[mt][nt] = fzero;
#pragma unroll
  for (int kt = 0; kt < 4; ++kt) {
    s16x8 a[4], bq[2];
#pragma unroll
    for (int mt = 0; mt < 4; ++mt)
      a[mt] = *(const s16x8*)(Xs + xrow[mt] + kt * 32 + wq8);
#pragma unroll
    for (int nt = 0; nt < 2; ++nt)
      bq[nt] = *(const s16x8*)(wT + (size_t)(h * 32 + nt * 16 + l16) * 128 + kt * 32 + wq8);
#pragma unroll
    for (int mt = 0; mt < 4; ++mt)
#pragma unroll
      for (int nt = 0; nt < 2; ++nt)
        accq[mt][nt] = mfma_bf16(a[mt], bq[nt], accq[mt][nt]);
  }
#pragma unroll
  for (int nt = 0; nt < 2; ++nt) {
    const int col = nt * 16 + l16;
    const float bq_ = qkv_b[h * 32 + col] * SCALE;   // Wq pre-scaled; scale bias to match
#pragma unroll
    for (int mt = 0; mt < 4; ++mt)
#pragma unroll
      for (int r = 0; r < 4; ++r)
        *(u16_a*)(qs + (mt * 16 + quad * 4 + r) * 40 + col) = f2bf(accq[mt][nt][r] + bq_);
  }
  asm volatile("" ::: "memory");
  s16x8 qf[4];
#pragma unroll
  for (int t4 = 0; t4 < 4; ++t4)
    qf[t4] = *(const s16x8_a*)(qs + (t4 * 16 + l16) * 40 + wq8);
  asm volatile("s_waitcnt lgkmcnt(0)" ::: "memory");   // qf in regs; buf0 reusable (WAR)
  __builtin_amdgcn_sched_barrier(0);                   // rule #18: pin vs compiler hoisting

  // ================= QKV pass A2: k -> buf0 (overwrite) -> kf regs =================
  f32x4 acck[4][2];
#pragma unroll
  for (int mt = 0; mt < 4; ++mt)
#pragma unroll
    for (int nt = 0; nt < 2; ++nt) acck[mt][nt] = fzero;
#pragma unroll
  for (int kt = 0; kt < 4; ++kt) {
    s16x8 a[4], bk[2];
#pragma unroll
    for (int mt = 0; mt < 4; ++mt)
      a[mt] = *(const s16x8*)(Xs + xrow[mt] + kt * 32 + wq8);
#pragma unroll
    for (int nt = 0; nt < 2; ++nt)
      bk[nt] = *(const s16x8*)(wT + (size_t)(128 + h * 32 + nt * 16 + l16) * 128 + kt * 32 + wq8);
#pragma unroll
    for (int mt = 0; mt < 4; ++mt)
#pragma unroll
      for (int nt = 0; nt < 2; ++nt)
        acck[mt][nt] = mfma_bf16(a[mt], bk[nt], acck[mt][nt]);
  }
#pragma unroll
  for (int nt = 0; nt < 2; ++nt) {
    const int col = nt * 16 + l16;
    const float bk_ = qkv_b[128 + h * 32 + col];
#pragma unroll
    for (int mt = 0; mt < 4; ++mt)
#pragma unroll
      for (int r = 0; r < 4; ++r)
        *(u16_a*)(ks + (mt * 16 + quad * 4 + r) * 40 + col) = f2bf(acck[mt][nt][r] + bk_);
  }
  asm volatile("" ::: "memory");
  s16x8 kf[4];
#pragma unroll
  for (int t4 = 0; t4 < 4; ++t4)
    kf[t4] = *(const s16x8_a*)(ks + (t4 * 16 + l16) * 40 + wq8);
  asm volatile("s_waitcnt lgkmcnt(0)" ::: "memory");   // kf in regs; buf0 reusable for P
  __builtin_amdgcn_sched_barrier(0);

  // ================= QKV pass B: v -> regs -> vT (buf1, virgin) =================
  f32x4 accv[4][2];
#pragma unroll
  for (int mt = 0; mt < 4; ++mt)
#pragma unroll
    for (int nt = 0; nt < 2; ++nt) accv[mt][nt] = fzero;
#pragma unroll
  for (int kt = 0; kt < 4; ++kt) {
    s16x8 a[4], bv[2];
#pragma unroll
    for (int mt = 0; mt < 4; ++mt)
      a[mt] = *(const s16x8*)(Xs + xrow[mt] + kt * 32 + wq8);
#pragma unroll
    for (int nt = 0; nt < 2; ++nt)
      bv[nt] = *(const s16x8*)(wT + (size_t)(256 + h * 32 + nt * 16 + l16) * 128 + kt * 32 + wq8);
#pragma unroll
    for (int mt = 0; mt < 4; ++mt)
#pragma unroll
      for (int nt = 0; nt < 2; ++nt)
        accv[mt][nt] = mfma_bf16(a[mt], bv[nt], accv[mt][nt]);
  }
#pragma unroll
  for (int nt = 0; nt < 2; ++nt) {
    const float bv_ = qkv_b[256 + h * 32 + nt * 16 + l16];
#pragma unroll
    for (int mt = 0; mt < 4; ++mt)
#pragma unroll
      for (int r = 0; r < 4; ++r) {
        const int row = mt * 16 + quad * 4 + r;     // token
        const int col = nt * 16 + l16;              // d
        *(u16_a*)(vt + col * 72 + row) = f2bf(accv[mt][nt][r] + bv_);
      }
  }

  // ---- S = q k^T (baseline) ----
  f32x4 s[4][4];
#pragma unroll
  for (int mt = 0; mt < 4; ++mt)
#pragma unroll
    for (int nt = 0; nt < 4; ++nt)
      s[mt][nt] = mfma_bf16(qf[mt], kf[nt], fzero);

  // ---- logits + rpb + mask; row softmax (baseline); P half0 -> LDS, half1 held ----
  const float* maskw = mask + (size_t)(w & 63) * (NTOK * NTOK);
  const float* rpbh  = rpb + h * (NTOK * NTOK);
  float rinv[4][4];
  unsigned int pHold[4][4];                          // packed bf16x2: j-tiles 2,3
#pragma unroll
  for (int mt = 0; mt < 4; ++mt) {
#pragma unroll
    for (int r = 0; r < 4; ++r) {
      const int i = mt * 16 + quad * 4 + r;
      float vals[4];
      float vmax = -1e30f;
#pragma unroll
      for (int nt = 0; nt < 4; ++nt) {
        const int j = nt * 16 + l16;
        float v = -1e30f;                            // pad cols -> P=0
        if (i < NTOK && j < NTOK) {
          const int ij = i * NTOK + j;
          v = s[mt][nt][r] + rpbh[ij] + maskw[ij];
        }
        vals[nt] = v;
        vmax = fmaxf(vmax, v);
      }
#pragma unroll
      for (int off = 1; off < 16; off <<= 1)         // row spans 16 lanes of this quad-group
        vmax = fmaxf(vmax, __shfl_xor(vmax, off, 64));
      float rsum = 0.f;
#pragma unroll
      for (int nt = 0; nt < 4; ++nt) {
        const float e = __expf(vals[nt] - vmax);
        vals[nt] = e;
        rsum += e;
      }
#pragma unroll
      for (int off = 1; off < 16; off <<= 1)
        rsum += __shfl_xor(rsum, off, 64);
      rinv[mt][r] = 1.f / rsum;                      // normalization deferred to AO write
      *(u16_a*)(ps + i * 40 + l16)      = f2bf(vals[0]);
      *(u16_a*)(ps + i * 40 + 16 + l16) = f2bf(vals[1]);
      pHold[mt][r] = (unsigned int)f2bf(vals[2]) | ((unsigned int)f2bf(vals[3]) << 16);
    }
  }

  // ================= O = P v (M=64,N=32,K=64), half-K ping-pong on P buffer =============
  f32x4 o[4][2];
#pragma unroll
  for (int mt = 0; mt < 4; ++mt)
#pragma unroll
    for (int nt = 0; nt < 2; ++nt) o[mt][nt] = fzero;
  {
    s16x8 pf[4], vf[2];
#pragma unroll
    for (int mt = 0; mt < 4; ++mt)
      pf[mt] = *(const s16x8_a*)(ps + (mt * 16 + l16) * 40 + wq8);
#pragma unroll
    for (int nt = 0; nt < 2; ++nt)
      vf[nt] = *(const s16x8_a*)(vt + (nt * 16 + l16) * 72 + wq8);
#pragma unroll
    for (int mt = 0; mt < 4; ++mt)
#pragma unroll
      for (int nt = 0; nt < 2; ++nt)
        o[mt][nt] = mfma_bf16(pf[mt], vf[nt], o[mt][nt]);
  }
  asm volatile("s_waitcnt lgkmcnt(0)" ::: "memory");   // kt0 reads drained before overwrite
  __builtin_amdgcn_sched_barrier(0);
#pragma unroll
  for (int mt = 0; mt < 4; ++mt)
#pragma unroll
    for (int r = 0; r < 4; ++r) {
      const int i = mt * 16 + quad * 4 + r;
      *(u16_a*)(ps + i * 40 + l16)      = (unsigned short)(pHold[mt][r] & 0xFFFFu);
      *(u16_a*)(ps + i * 40 + 16 + l16) = (unsigned short)(pHold[mt][r] >> 16);
    }
  asm volatile("" ::: "memory");       // stores ordered before kt1 reads
  {
    s16x8 pf[4], vf[2];
#pragma unroll
    for (int mt = 0; mt < 4; ++mt)
      pf[mt] = *(const s16x8_a*)(ps + (mt * 16 + l16) * 40 + wq8);
#pragma unroll
    for (int nt = 0; nt < 2; ++nt)
      vf[nt] = *(const s16x8_a*)(vt + (nt * 16 + l16) * 72 + 32 + wq8);
#pragma unroll
    for (int mt = 0; mt < 4; ++mt)
#pragma unroll
      for (int nt = 0; nt < 2; ++nt)
        o[mt][nt] = mfma_bf16(pf[mt], vf[nt], o[mt][nt]);
  }

  // ================= AO -> LDS (baseline), proj (baseline) =================
  __syncthreads();                     // barrier 2: all waves done with priv/Xs
#pragma unroll
  for (int mt = 0; mt < 4; ++mt)
#pragma unroll
    for (int nt = 0; nt < 2; ++nt)
#pragma unroll
      for (int r = 0; r < 4; ++r) {
        const int row = mt * 16 + quad * 4 + r;
        *(u16_a*)(ao + row * 136 + h * 32 + nt * 16 + l16) = f2bf(o[mt][nt][r] * rinv[mt][r]);
      }
  __syncthreads();                     // barrier 3: AO published

  f32x4 po[4][2];
#pragma unroll
  for (int mt = 0; mt < 4; ++mt)
#pragma unroll
    for (int nt = 0; nt < 2; ++nt) po[mt][nt] = fzero;
#pragma unroll
  for (int kt = 0; kt < 4; ++kt) {
    s16x8 a[4], b[2];
#pragma unroll
    for (int mt = 0; mt < 4; ++mt)
      a[mt] = *(const s16x8_a*)(ao + (mt * 16 + l16) * 136 + kt * 32 + wq8);
#pragma unroll
    for (int nt = 0; nt < 2; ++nt)
      b[nt] = *(const s16x8*)(pT + (size_t)(h * 32 + nt * 16 + l16) * 128 + kt * 32 + wq8);
#pragma unroll
    for (int mt = 0; mt < 4; ++mt)
#pragma unroll
      for (int nt = 0; nt < 2; ++nt)
        po[mt][nt] = mfma_bf16(a[mt], b[nt], po[mt][nt]);
  }
  float* outw = out + (size_t)w * (NTOK * CH);
#pragma unroll
  for (int nt = 0; nt < 2; ++nt) {
    const int col = h * 32 + nt * 16 + l16;
    const float pb = proj_b[col];
#pragma unroll
    for (int mt = 0; mt < 4; ++mt)
#pragma unroll
      for (int r = 0; r < 4; ++r) {
        const int row = mt * 16 + quad * 4 + r;
        if (row < NTOK) outw[row * CH + col] = po[mt][nt][r] + pb;
      }
  }
}

extern "C" void kernel_launch(void* const* d_in, const int* in_sizes, int n_in,
                              void* d_out, int out_size, void* d_ws, size_t ws_size,
                              hipStream_t stream) {
  (void)in_sizes; (void)n_in; (void)out_size; (void)ws_size;
  const float* x          = (const float*)d_in[0];
  const float* qkv_w      = (const float*)d_in[1];
  const float* qkv_b      = (const float*)d_in[2];
  const float* proj_w     = (const float*)d_in[3];
  const float* proj_b     = (const float*)d_in[4];
  const float* bias_table = (const float*)d_in[5];
  const float* mask       = (const float*)d_in[6];
  float* out = (float*)d_out;

  unsigned short* wT = (unsigned short*)d_ws;          // 384*128 bf16
  unsigned short* pT = wT + 384 * 128;                 // 128*128 bf16
  float* rpb = (float*)(pT + 128 * 128);               // 4*49*49 f32 (@131072 B)

  const int prep_items = 384 * 128 + 128 * 128 + NHEAD * NTOK * NTOK;
  prep_kernel<<<(prep_items + 255) / 256, 256, 0, stream>>>(qkv_w, proj_w, bias_table,
                                                            wT, pT, rpb);
  attn_fused_kernel<<<4096, 256, 0, stream>>>(x, qkv_b, proj_b, mask, wT, pT, rpb, out);
}